// Round 13
// baseline (251.016 us; speedup 1.0000x reference)
//
#include <hip/hip_runtime.h>
#include <hip/hip_bf16.h>
#include <stdint.h>

// MoE: B=4,S=2048,D=512,F=2048,E=8,K=2.  T = B*S = 8192 tokens.
#define TT 8192
#define DD 512
#define FF 2048
#define EE 8
#define MAXT 136   // max row-tiles at BM=128
#define MAXT2 72   // max row-tiles at BM=256

typedef __attribute__((ext_vector_type(8))) short bf16x8;
typedef __attribute__((ext_vector_type(4))) float f32x4;

static __device__ __forceinline__ unsigned short f2b(float f) {
  union { __hip_bfloat16 b; unsigned short u; } cv;
  cv.b = __float2bfloat16(f);
  return cv.u;
}
static __device__ __forceinline__ float b2f(unsigned short u) {
  union { unsigned int i; float f; } cv;
  cv.i = ((unsigned int)u) << 16;
  return cv.f;
}

// async global->LDS, 16B per lane. LDS dest must be wave_base + lane*16.
static __device__ __forceinline__ void gload16(const void* g, void* l) {
  __builtin_amdgcn_global_load_lds(
      (const __attribute__((address_space(1))) unsigned int*)g,
      (__attribute__((address_space(3))) unsigned int*)l, 16, 0, 0);
}

#define VMCNT4  asm volatile("s_waitcnt vmcnt(4)" ::: "memory")
#define VMCNT0  asm volatile("s_waitcnt vmcnt(0)" ::: "memory")
#define BARX    asm volatile("s_barrier" ::: "memory")
#define PRIO1   __builtin_amdgcn_s_setprio(1)
#define PRIO0   __builtin_amdgcn_s_setprio(0)

// ---------------- prep: gate logits (fp32) + x->bf16 --------------------
__launch_bounds__(256)
__global__ void k_prep(const float* __restrict__ x, const float* __restrict__ Wg,
                       unsigned short* __restrict__ xb,
                       int* __restrict__ te, float* __restrict__ tw) {
  int wid = threadIdx.x >> 6, lane = threadIdx.x & 63;
  int t = blockIdx.x * 4 + wid;
  const float* xr = x + (size_t)t * DD;
  unsigned short* xbr = xb + (size_t)t * DD;
  int d0 = lane * 8;

  float4 v0 = *(const float4*)(xr + d0);
  float4 v1 = *(const float4*)(xr + d0 + 4);
  ushort4 o0, o1;
  o0.x = f2b(v0.x); o0.y = f2b(v0.y); o0.z = f2b(v0.z); o0.w = f2b(v0.w);
  o1.x = f2b(v1.x); o1.y = f2b(v1.y); o1.z = f2b(v1.z); o1.w = f2b(v1.w);
  *(ushort4*)(xbr + d0) = o0;
  *(ushort4*)(xbr + d0 + 4) = o1;

  float xv[8] = {v0.x, v0.y, v0.z, v0.w, v1.x, v1.y, v1.z, v1.w};
  float acc[EE];
#pragma unroll
  for (int e = 0; e < EE; e++) acc[e] = 0.f;
#pragma unroll
  for (int j = 0; j < 8; j++) {
    const float* wg = Wg + (size_t)(d0 + j) * EE;
    float4 a = *(const float4*)wg;
    float4 b = *(const float4*)(wg + 4);
    acc[0] += xv[j] * a.x; acc[1] += xv[j] * a.y; acc[2] += xv[j] * a.z; acc[3] += xv[j] * a.w;
    acc[4] += xv[j] * b.x; acc[5] += xv[j] * b.y; acc[6] += xv[j] * b.z; acc[7] += xv[j] * b.w;
  }
#pragma unroll
  for (int e = 0; e < EE; e++)
    for (int o = 32; o; o >>= 1) acc[e] += __shfl_xor(acc[e], o);
  if (lane == 0) {
    int e1 = 0; float v1m = acc[0];
#pragma unroll
    for (int e = 1; e < EE; e++) if (acc[e] > v1m) { v1m = acc[e]; e1 = e; }
    int e2 = -1; float v2m = -INFINITY;
#pragma unroll
    for (int e = 0; e < EE; e++) if (e != e1 && acc[e] > v2m) { v2m = acc[e]; e2 = e; }
    float ex = __expf(v2m - v1m);
    float w1 = 1.f / (1.f + ex);
    float w2 = ex / (1.f + ex);
    te[t * 2] = e1; te[t * 2 + 1] = e2;
    tw[t * 2] = w1; tw[t * 2 + 1] = w2;
  }
}

// ------------- transpose+convert all weights, one launch (z=0..23) ----------
__global__ void k_tcvt_all(const float* __restrict__ W, const float* __restrict__ V,
                           const float* __restrict__ W2, unsigned short* __restrict__ Wt,
                           unsigned short* __restrict__ Vt, unsigned short* __restrict__ W2t) {
  __shared__ float tile[32][33];
  int z = blockIdx.y;
  const float* src; unsigned short* dst; int N, nbx;
  if (z < 16) {
    int e = z & 7;
    size_t base = (size_t)e * DD * FF;
    src = (z < 8 ? W : V) + base;
    dst = (z < 8 ? Wt : Vt) + base;
    N = FF; nbx = FF / 32;          // in [DD][FF] -> out [FF][DD]
  } else {
    int e = z - 16;
    size_t base = (size_t)e * DD * FF;
    src = W2 + base; dst = W2t + base;
    N = DD; nbx = DD / 32;          // in [FF][DD] -> out [DD][FF]
  }
  int M = (z < 16) ? DD : FF;
  int bx = blockIdx.x;
  int cb = (bx % nbx) * 32, rb = (bx / nbx) * 32;
  int tx = threadIdx.x, ty = threadIdx.y;
#pragma unroll
  for (int i = 0; i < 4; i++)
    tile[ty + i * 8][tx] = src[(size_t)(rb + ty + i * 8) * N + cb + tx];
  __syncthreads();
#pragma unroll
  for (int i = 0; i < 4; i++)
    dst[(size_t)(cb + ty + i * 8) * M + rb + tx] = f2b(tile[tx][ty + i * 8]);
}

// ---------------- routing: single-block deterministic counting sort --------
__launch_bounds__(1024)
__global__ void k_route(const int* __restrict__ te, const float* __restrict__ tw,
                        int* __restrict__ ctrl, int* __restrict__ perm,
                        float* __restrict__ pw, int* __restrict__ tileE,
                        int* __restrict__ tileRow, int* __restrict__ inv,
                        int* __restrict__ tileE2, int* __restrict__ tileRow2) {
  __shared__ int wsum[17][EE];
  __shared__ int ebase[EE];
  int tid = threadIdx.x;
  int lane = tid & 63, wid = tid >> 6;
  int myte[16]; float mytw[16];
  int c[EE];
#pragma unroll
  for (int e = 0; e < EE; e++) c[e] = 0;
  int s0 = tid * 16;
#pragma unroll
  for (int j = 0; j < 16; j++) {
    myte[j] = te[s0 + j];
    mytw[j] = tw[s0 + j];
#pragma unroll
    for (int e = 0; e < EE; e++) if (myte[j] == e) c[e]++;
  }
  int incl[EE];
#pragma unroll
  for (int e = 0; e < EE; e++) incl[e] = c[e];
  for (int off = 1; off < 64; off <<= 1) {
#pragma unroll
    for (int e = 0; e < EE; e++) {
      int v = __shfl_up(incl[e], off);
      if (lane >= off) incl[e] += v;
    }
  }
  if (lane == 63)
#pragma unroll
    for (int e = 0; e < EE; e++) wsum[wid][e] = incl[e];
  __syncthreads();
  if (tid < EE) {
    int s = 0;
    for (int w = 0; w < 16; w++) { int v = wsum[w][tid]; wsum[w][tid] = s; s += v; }
    wsum[16][tid] = s;
  }
  __syncthreads();
  if (tid == 0) {
    int s = 0, nt = 0, nt2 = 0;
    for (int e = 0; e < EE; e++) {
      int cnt = wsum[16][e];
      ebase[e] = s; ctrl[8 + e] = s; ctrl[e] = cnt;
      for (int i = 0; i < cnt; i += 128) { tileE[nt] = e; tileRow[nt] = s + i; nt++; }
      for (int i = 0; i < cnt; i += 256) { tileE2[nt2] = e; tileRow2[nt2] = s + i; nt2++; }
      s += cnt;
    }
    ctrl[16] = s; ctrl[17] = nt; ctrl[18] = nt2;
  }
  __syncthreads();
#pragma unroll
  for (int e = 0; e < EE; e++) {
    int p = ebase[e] + wsum[wid][e] + incl[e] - c[e];
#pragma unroll
    for (int j = 0; j < 16; j++) {
      if (myte[j] == e) {
        perm[p] = (s0 + j) >> 1;
        pw[p] = mytw[j];
        inv[s0 + j] = p;
        p++;
      }
    }
  }
}

// ---------------- GEMM1: h[pos][f] = pw * silu(x@W) * (x@V) -----------------
// 8-phase template: BM=256 x 128 f-cols (W+V -> 256 B-rows), BK=64, 8 waves
// 2Mx4N. Region-safe staging: each LDS quarter is overwritten only in phases
// strictly after its complete read set (As fully read by P3/P7, Bs by P2/P6).
// One 2-load stage op per phase; vmcnt(4) only at P4/P8.
__launch_bounds__(512, 2)
__global__ void k_ffn1(const unsigned short* __restrict__ xb,
                       const unsigned short* __restrict__ Wt,
                       const unsigned short* __restrict__ Vt,
                       const int* __restrict__ perm, const float* __restrict__ pw,
                       const int* __restrict__ ctrl, const int* __restrict__ tileE2,
                       const int* __restrict__ tileRow2,
                       unsigned short* __restrict__ h) {
  int ti = blockIdx.y;
  if (ti >= ctrl[18]) return;
  int e = tileE2[ti];
  int row0 = tileRow2[ti];
  int last = ctrl[8 + e] + ctrl[e] - 1;
  int f0 = blockIdx.x * 128;

  extern __shared__ short lds[];
  short* As0 = lds;            // [256*64]
  short* As1 = lds + 16384;
  short* Bs0 = lds + 32768;
  short* Bs1 = lds + 49152;

  int t = threadIdx.x;
  int lane = t & 63, wid = t >> 6;
  int wr = wid >> 2, wc = wid & 3;
  int lrow = lane & 15, lk = lane >> 4, l7 = lane & 7;

  // staging: thread t covers rows (t>>3)+j*64, phys 16B slot t&7; source is
  // pre-swizzled (logical slot = phys ^ (row&7)) so LDS dest stays linear.
  int w64 = t >> 3;
  int lsl = ((t & 7) ^ (w64 & 7)) * 8;
  int dof0 = (w64 + 0) * 64 + (t & 7) * 8;
  int dof1 = (w64 + 64) * 64 + (t & 7) * 8;
  int dof2 = (w64 + 128) * 64 + (t & 7) * 8;
  int dof3 = (w64 + 192) * 64 + (t & 7) * 8;
  int ar0 = row0 + w64;        if (ar0 > last) ar0 = last;
  int ar1 = row0 + w64 + 64;   if (ar1 > last) ar1 = last;
  int ar2 = row0 + w64 + 128;  if (ar2 > last) ar2 = last;
  int ar3 = row0 + w64 + 192;  if (ar3 > last) ar3 = last;
  const unsigned short* ap0 = xb + (size_t)perm[ar0] * DD + lsl;
  const unsigned short* ap1 = xb + (size_t)perm[ar1] * DD + lsl;
  const unsigned short* ap2 = xb + (size_t)perm[ar2] * DD + lsl;
  const unsigned short* ap3 = xb + (size_t)perm[ar3] * DD + lsl;
  // B LDS rows: c<32: W col grp, c^=32 flag -> V. row j*64+w64: w64<32 W, else V.
  const unsigned short* bbase = ((w64 < 32) ? Wt : Vt)
      + ((size_t)e * FF + f0 + (w64 & 31)) * DD + lsl;

#define SA0(Ad, kt) do { gload16(ap0 + (kt) * 64, &Ad[dof0]); \
                         gload16(ap1 + (kt) * 64, &Ad[dof1]); } while (0)
#define SA1(Ad, kt) do { gload16(ap2 + (kt) * 64, &Ad[dof2]); \
                         gload16(ap3 + (kt) * 64, &Ad[dof3]); } while (0)
#define SB0(Bd, kt) do { gload16(bbase + (kt) * 64,            &Bd[dof0]); \
                         gload16(bbase + 32 * DD + (kt) * 64,  &Bd[dof1]); } while (0)
#define SB1(Bd, kt) do { gload16(bbase + 64 * DD + (kt) * 64,  &Bd[dof2]); \
                         gload16(bbase + 96 * DD + (kt) * 64,  &Bd[dof3]); } while (0)

  bf16x8 af[4][2], bfw[2][2], bfv[2][2];
  f32x4 zz = {0.f, 0.f, 0.f, 0.f};
  f32x4 accw[8][2], accv[8][2];
#pragma unroll
  for (int m = 0; m < 8; m++)
#pragma unroll
    for (int n = 0; n < 2; n++) { accw[m][n] = zz; accv[m][n] = zz; }

#define AREAD(Ad, mh) do { \
    _Pragma("unroll") \
    for (int m_ = 0; m_ < 4; m_++) \
      _Pragma("unroll") \
      for (int ks_ = 0; ks_ < 2; ks_++) \
        af[m_][ks_] = *(bf16x8*)&Ad[(wr * 128 + ((mh) * 4 + m_) * 16 + lrow) * 64 + ((ks_ * 4 + lk) ^ l7) * 8]; \
  } while (0)
#define BWREAD(Bd) do { \
    _Pragma("unroll") \
    for (int n_ = 0; n_ < 2; n_++) \
      _Pragma("unroll") \
      for (int ks_ = 0; ks_ < 2; ks_++) \
        bfw[n_][ks_] = *(bf16x8*)&Bd[(wc * 64 + n_ * 16 + lrow) * 64 + ((ks_ * 4 + lk) ^ l7) * 8]; \
  } while (0)
#define BVREAD(Bd) do { \
    _Pragma("unroll") \
    for (int n_ = 0; n_ < 2; n_++) \
      _Pragma("unroll") \
      for (int ks_ = 0; ks_ < 2; ks_++) \
        bfv[n_][ks_] = *(bf16x8*)&Bd[(wc * 64 + 32 + n_ * 16 + lrow) * 64 + ((ks_ * 4 + lk) ^ l7) * 8]; \
  } while (0)
#define MFW(mh) do { PRIO1; \
    _Pragma("unroll") \
    for (int m_ = 0; m_ < 4; m_++) \
      _Pragma("unroll") \
      for (int n_ = 0; n_ < 2; n_++) \
        _Pragma("unroll") \
        for (int ks_ = 0; ks_ < 2; ks_++) \
          accw[(mh) * 4 + m_][n_] = __builtin_amdgcn_mfma_f32_16x16x32_bf16(af[m_][ks_], bfw[n_][ks_], accw[(mh) * 4 + m_][n_], 0, 0, 0); \
    PRIO0; } while (0)
#define MFV(mh) do { PRIO1; \
    _Pragma("unroll") \
    for (int m_ = 0; m_ < 4; m_++) \
      _Pragma("unroll") \
      for (int n_ = 0; n_ < 2; n_++) \
        _Pragma("unroll") \
        for (int ks_ = 0; ks_ < 2; ks_++) \
          accv[(mh) * 4 + m_][n_] = __builtin_amdgcn_mfma_f32_16x16x32_bf16(af[m_][ks_], bfv[n_][ks_], accv[(mh) * 4 + m_][n_], 0, 0, 0); \
    PRIO0; } while (0)

  // prologue: kt0 -> buf0 (8 loads), kt1 B-halves -> Bs1 (4 loads)
  SB0(Bs0, 0); SB1(Bs0, 0); SA0(As0, 0); SA1(As0, 0);
  SB0(Bs1, 1); SB1(Bs1, 1);
  VMCNT4; BARX;

#pragma unroll 1
  for (int i = 0; i < 4; i++) {     // K = 512 = 4 iters x 2 K-tiles x 64
    int kt1 = 2 * i + 1, kt2 = 2 * i + 2, kt3 = 2 * i + 3;
    bool nl = (i < 3);
    // P1: buf0 mh0 x W; stage As1 h0 (kt1)  [As1 prev fully read at P7 prev]
    AREAD(As0, 0); BWREAD(Bs0);
    SA0(As1, kt1);
    BARX; MFW(0); BARX;
    // P2: mh0 x V; stage As1 h1 (kt1)
    BVREAD(Bs0);
    SA1(As1, kt1);
    BARX; MFV(0); BARX;
    // P3: mh1 x V; stage Bs0 h0 (kt2)  [Bs0 fully read at P2]
    AREAD(As0, 1);
    if (nl) SB0(Bs0, kt2);
    BARX; MFV(1); BARX;
    // P4: mh1 x W; stage Bs0 h1 (kt2); wait buf1 (kt1) landed
    if (nl) { SB1(Bs0, kt2); VMCNT4; } else { VMCNT0; }
    BARX; MFW(1); BARX;
    // P5: buf1 mh0 x W; stage As0 h0 (kt2)  [As0 fully read at P3]
    AREAD(As1, 0); BWREAD(Bs1);
    if (nl) SA0(As0, kt2);
    BARX; MFW(0); BARX;
    // P6: mh0 x V; stage As0 h1 (kt2)
    BVREAD(Bs1);
    if (nl) SA1(As0, kt2);
    BARX; MFV(0); BARX;
    // P7: mh1 x V; stage Bs1 h0 (kt3)  [Bs1 fully read at P6]
    AREAD(As1, 1);
    if (nl) SB0(Bs1, kt3);
    BARX; MFV(1); BARX;
    // P8: mh1 x W; stage Bs1 h1 (kt3); wait buf0 (kt2) landed
    if (nl) { SB1(Bs1, kt3); VMCNT4; } else { VMCNT0; }
    BARX; MFW(1); BARX;
  }
#undef SA0
#undef SA1
#undef SB0
#undef SB1
#undef AREAD
#undef BWREAD
#undef BVREAD
#undef MFW
#undef MFV

  // epilogue: silu(w)*v*gate, bf16 store
#pragma unroll
  for (int mf = 0; mf < 8; mf++) {
    int rbase = row0 + wr * 128 + mf * 16 + lk * 4;
#pragma unroll
    for (int reg = 0; reg < 4; reg++) {
      int r = rbase + reg;
      if (r > last) continue;
      float pwv = pw[r];
      size_t hrow = (size_t)r * FF;
#pragma unroll
      for (int nf = 0; nf < 2; nf++) {
        float a = accw[mf][nf][reg];
        float b = accv[mf][nf][reg];
        float hv = a / (1.f + __expf(-a)) * b * pwv;
        h[hrow + f0 + wc * 32 + nf * 16 + lrow] = f2b(hv);
      }
    }
  }
}

// ---------------- GEMM2: yp[pos][d] = h[pos] @ W2t[e]  (bf16 out) -----------
// 128x128 tile, BK=32 over K=F=2048, 4 waves 2x2, acc[4][4], 2-stage dbuf.
__launch_bounds__(256)
__global__ void k_ffn2(const unsigned short* __restrict__ h,
                       const unsigned short* __restrict__ W2t,
                       const int* __restrict__ ctrl,
                       const int* __restrict__ tileE, const int* __restrict__ tileRow,
                       unsigned short* __restrict__ yp) {
  int ti = blockIdx.y;
  if (ti >= ctrl[17]) return;
  int e = tileE[ti];
  int row0 = tileRow[ti];
  int last = ctrl[8 + e] + ctrl[e] - 1;
  int d0 = blockIdx.x * 128;

  __shared__ __align__(16) short As[2][128 * 32];
  __shared__ __align__(16) short Bs[2][128 * 32];

  int tid = threadIdx.x;
  int lane = tid & 63, wid = tid >> 6;
  int wm = (wid >> 1) * 64, wn = (wid & 1) * 64;

  int sl = (((tid & 3) ^ ((tid >> 3) & 3))) * 8;

  int ar1 = row0 + (tid >> 2); if (ar1 > last) ar1 = last;
  int ar2 = row0 + (tid >> 2) + 64; if (ar2 > last) ar2 = last;
  const unsigned short* agp1 = h + (size_t)ar1 * FF + sl;
  const unsigned short* agp2 = h + (size_t)ar2 * FF + sl;
  const unsigned short* bgp1 = W2t + ((size_t)e * DD + d0 + (tid >> 2)) * FF + sl;
  const unsigned short* bgp2 = bgp1 + (size_t)64 * FF;

#define STAGE2(buf, k0) do { \
    gload16(agp1 + (k0), &As[buf][tid * 8]); \
    gload16(agp2 + (k0), &As[buf][(tid + 256) * 8]); \
    gload16(bgp1 + (k0), &Bs[buf][tid * 8]); \
    gload16(bgp2 + (k0), &Bs[buf][(tid + 256) * 8]); \
  } while (0)

  f32x4 zz = {0.f, 0.f, 0.f, 0.f};
  f32x4 acc[4][4];
#pragma unroll
  for (int m = 0; m < 4; m++)
#pragma unroll
    for (int n = 0; n < 4; n++) acc[m][n] = zz;

  int lrow = lane & 15;
  int jx = (((lane >> 4) ^ ((lane >> 1) & 3))) * 8;

#define COMP2(buf) do { \
    bf16x8 a[4], b[4]; \
    _Pragma("unroll") \
    for (int m = 0; m < 4; m++) a[m] = *(bf16x8*)&As[buf][(wm + m * 16 + lrow) * 32 + jx]; \
    _Pragma("unroll") \
    for (int n = 0; n < 4; n++) b[n] = *(bf16x8*)&Bs[buf][(wn + n * 16 + lrow) * 32 + jx]; \
    _Pragma("unroll") \
    for (int m = 0; m < 4; m++) \
      _Pragma("unroll") \
      for (int n = 0; n < 4; n++) \
        acc[m][n] = __builtin_amdgcn_mfma_f32_16x16x32_bf16(a[m], b[n], acc[m][n], 0, 0, 0); \
  } while (0)

  STAGE2(0, 0);
  __syncthreads();
#pragma unroll 1
  for (int ks = 0; ks < 64; ks += 2) {
    if (ks + 1 < 64) STAGE2(1, (ks + 1) * 32);
    COMP2(0);
    __syncthreads();
    if (ks + 2 < 64) STAGE2(0, (ks + 2) * 32);
    COMP2(1);
    __syncthreads();
  }
#undef STAGE2
#undef COMP2

#pragma unroll
  for (int m = 0; m < 4; m++) {
    int rbase = row0 + wm + m * 16 + (lane >> 4) * 4;
#pragma unroll
    for (int reg = 0; reg < 4; reg++) {
      int r = rbase + reg;
      if (r > last) continue;
      unsigned short* ypr = yp + (size_t)r * DD + d0;
#pragma unroll
      for (int n = 0; n < 4; n++)
        ypr[wn + n * 16 + lrow] = f2b(acc[m][n][reg]);
    }
  }
}

// ---------------- gather: y[t] = yp[inv[2t]] + yp[inv[2t+1]]  (bf16 in) -----
__launch_bounds__(256)
__global__ void k_gather(const unsigned short* __restrict__ yp,
                         const int* __restrict__ inv, float* __restrict__ y) {
  int i = blockIdx.x * 256 + threadIdx.x;   // over TT*64 groups of 8 cols
  int t = i >> 6, seg = (i & 63) * 8;
  int pa = inv[2 * t], pb = inv[2 * t + 1];
  bf16x8 a = *(const bf16x8*)(yp + (size_t)pa * DD + seg);
  bf16x8 b = *(const bf16x8*)(yp + (size_t)pb * DD + seg);
  float* yr = y + (size_t)t * DD + seg;
  float4 o0, o1;
  o0.x = b2f((unsigned short)a[0]) + b2f((unsigned short)b[0]);
  o0.y = b2f((unsigned short)a[1]) + b2f((unsigned short)b[1]);
  o0.z = b2f((unsigned short)a[2]) + b2f((unsigned short)b[2]);
  o0.w = b2f((unsigned short)a[3]) + b2f((unsigned short)b[3]);
  o1.x = b2f((unsigned short)a[4]) + b2f((unsigned short)b[4]);
  o1.y = b2f((unsigned short)a[5]) + b2f((unsigned short)b[5]);
  o1.z = b2f((unsigned short)a[6]) + b2f((unsigned short)b[6]);
  o1.w = b2f((unsigned short)a[7]) + b2f((unsigned short)b[7]);
  *(float4*)yr = o0;
  *(float4*)(yr + 4) = o1;
}

extern "C" void kernel_launch(void* const* d_in, const int* in_sizes, int n_in,
                              void* d_out, int out_size, void* d_ws, size_t ws_size,
                              hipStream_t stream) {
  const float* x  = (const float*)d_in[0];
  const float* Wg = (const float*)d_in[1];
  const float* W  = (const float*)d_in[2];
  const float* V  = (const float*)d_in[3];
  const float* W2 = (const float*)d_in[4];
  float* y = (float*)d_out;

  char* ws = (char*)d_ws;
  size_t off = 0;
  auto alloc = [&](size_t n) -> char* {
    char* p = ws + off;
    off += (n + 255) & ~(size_t)255;
    return p;
  };
  unsigned short* xb  = (unsigned short*)alloc((size_t)TT * DD * 2);
  unsigned short* Wt  = (unsigned short*)alloc((size_t)EE * DD * FF * 2);
  unsigned short* Vt  = (unsigned short*)alloc((size_t)EE * DD * FF * 2);
  unsigned short* W2t = (unsigned short*)alloc((size_t)EE * DD * FF * 2);
  unsigned short* h   = (unsigned short*)alloc((size_t)TT * 2 * FF * 2);
  int*   perm = (int*)alloc(TT * 2 * 4);
  float* pw   = (float*)alloc(TT * 2 * 4);
  int*   te   = (int*)alloc(TT * 2 * 4);
  float* tw   = (float*)alloc(TT * 2 * 4);
  int*   inv  = (int*)alloc(TT * 2 * 4);
  int*   ctrl = (int*)alloc(256);
  int*   tileE    = (int*)alloc(MAXT * 4);
  int*   tileRow  = (int*)alloc(MAXT * 4);
  int*   tileE2   = (int*)alloc(MAXT2 * 4);
  int*   tileRow2 = (int*)alloc(MAXT2 * 4);
  if (off > ws_size) return;

  // yp (16384x512 bf16 = 16.8 MB) aliases Wt (dead after ffn1).
  unsigned short* yp = (unsigned short*)Wt;

  hipFuncSetAttribute((const void*)k_ffn1,
                      hipFuncAttributeMaxDynamicSharedMemorySize, 131072);

  k_prep<<<TT / 4, 256, 0, stream>>>(x, Wg, xb, te, tw);
  k_tcvt_all<<<dim3(1024, 24), dim3(32, 8), 0, stream>>>(W, V, W2, Wt, Vt, W2t);
  k_route<<<1, 1024, 0, stream>>>(te, tw, ctrl, perm, pw, tileE, tileRow, inv, tileE2, tileRow2);
  k_ffn1<<<dim3(FF / 128, MAXT2), 512, 131072, stream>>>(xb, Wt, Vt, perm, pw, ctrl, tileE2, tileRow2, h);
  k_ffn2<<<dim3(DD / 128, MAXT), 256, 0, stream>>>(h, W2t, ctrl, tileE, tileRow, yp);
  k_gather<<<TT * 64 / 256, 256, 0, stream>>>(yp, inv, y);
}

// Round 14
// 240.423 us; speedup vs baseline: 1.0441x; 1.0441x over previous
//
#include <hip/hip_runtime.h>
#include <hip/hip_bf16.h>
#include <stdint.h>

// MoE: B=4,S=2048,D=512,F=2048,E=8,K=2.  T = B*S = 8192 tokens.
#define TT 8192
#define DD 512
#define FF 2048
#define EE 8
#define MAXT 136   // max row-tiles at BM=128

typedef __attribute__((ext_vector_type(8))) short bf16x8;
typedef __attribute__((ext_vector_type(4))) float f32x4;

static __device__ __forceinline__ unsigned short f2b(float f) {
  union { __hip_bfloat16 b; unsigned short u; } cv;
  cv.b = __float2bfloat16(f);
  return cv.u;
}
static __device__ __forceinline__ float b2f(unsigned short u) {
  union { unsigned int i; float f; } cv;
  cv.i = ((unsigned int)u) << 16;
  return cv.f;
}

// async global->LDS, 16B per lane. LDS dest must be wave_base + lane*16.
static __device__ __forceinline__ void gload16(const void* g, void* l) {
  __builtin_amdgcn_global_load_lds(
      (const __attribute__((address_space(1))) unsigned int*)g,
      (__attribute__((address_space(3))) unsigned int*)l, 16, 0, 0);
}

#define VMCNT12 asm volatile("s_waitcnt vmcnt(12)" ::: "memory")
#define VMCNT6  asm volatile("s_waitcnt vmcnt(6)" ::: "memory")
#define VMCNT0  asm volatile("s_waitcnt vmcnt(0)" ::: "memory")
#define BARX    asm volatile("s_barrier" ::: "memory")

// ---------------- prep: gate logits (fp32) + x->bf16 --------------------
__launch_bounds__(256)
__global__ void k_prep(const float* __restrict__ x, const float* __restrict__ Wg,
                       unsigned short* __restrict__ xb,
                       int* __restrict__ te, float* __restrict__ tw) {
  int wid = threadIdx.x >> 6, lane = threadIdx.x & 63;
  int t = blockIdx.x * 4 + wid;
  const float* xr = x + (size_t)t * DD;
  unsigned short* xbr = xb + (size_t)t * DD;
  int d0 = lane * 8;

  float4 v0 = *(const float4*)(xr + d0);
  float4 v1 = *(const float4*)(xr + d0 + 4);
  ushort4 o0, o1;
  o0.x = f2b(v0.x); o0.y = f2b(v0.y); o0.z = f2b(v0.z); o0.w = f2b(v0.w);
  o1.x = f2b(v1.x); o1.y = f2b(v1.y); o1.z = f2b(v1.z); o1.w = f2b(v1.w);
  *(ushort4*)(xbr + d0) = o0;
  *(ushort4*)(xbr + d0 + 4) = o1;

  float xv[8] = {v0.x, v0.y, v0.z, v0.w, v1.x, v1.y, v1.z, v1.w};
  float acc[EE];
#pragma unroll
  for (int e = 0; e < EE; e++) acc[e] = 0.f;
#pragma unroll
  for (int j = 0; j < 8; j++) {
    const float* wg = Wg + (size_t)(d0 + j) * EE;
    float4 a = *(const float4*)wg;
    float4 b = *(const float4*)(wg + 4);
    acc[0] += xv[j] * a.x; acc[1] += xv[j] * a.y; acc[2] += xv[j] * a.z; acc[3] += xv[j] * a.w;
    acc[4] += xv[j] * b.x; acc[5] += xv[j] * b.y; acc[6] += xv[j] * b.z; acc[7] += xv[j] * b.w;
  }
#pragma unroll
  for (int e = 0; e < EE; e++)
    for (int o = 32; o; o >>= 1) acc[e] += __shfl_xor(acc[e], o);
  if (lane == 0) {
    int e1 = 0; float v1m = acc[0];
#pragma unroll
    for (int e = 1; e < EE; e++) if (acc[e] > v1m) { v1m = acc[e]; e1 = e; }
    int e2 = -1; float v2m = -INFINITY;
#pragma unroll
    for (int e = 0; e < EE; e++) if (e != e1 && acc[e] > v2m) { v2m = acc[e]; e2 = e; }
    float ex = __expf(v2m - v1m);
    float w1 = 1.f / (1.f + ex);
    float w2 = ex / (1.f + ex);
    te[t * 2] = e1; te[t * 2 + 1] = e2;
    tw[t * 2] = w1; tw[t * 2 + 1] = w2;
  }
}

// ------------- transpose+convert all weights, one launch (z=0..23) ----------
__global__ void k_tcvt_all(const float* __restrict__ W, const float* __restrict__ V,
                           const float* __restrict__ W2, unsigned short* __restrict__ Wt,
                           unsigned short* __restrict__ Vt, unsigned short* __restrict__ W2t) {
  __shared__ float tile[32][33];
  int z = blockIdx.y;
  const float* src; unsigned short* dst; int N, nbx;
  if (z < 16) {
    int e = z & 7;
    size_t base = (size_t)e * DD * FF;
    src = (z < 8 ? W : V) + base;
    dst = (z < 8 ? Wt : Vt) + base;
    N = FF; nbx = FF / 32;          // in [DD][FF] -> out [FF][DD]
  } else {
    int e = z - 16;
    size_t base = (size_t)e * DD * FF;
    src = W2 + base; dst = W2t + base;
    N = DD; nbx = DD / 32;          // in [FF][DD] -> out [DD][FF]
  }
  int M = (z < 16) ? DD : FF;
  int bx = blockIdx.x;
  int cb = (bx % nbx) * 32, rb = (bx / nbx) * 32;
  int tx = threadIdx.x, ty = threadIdx.y;
#pragma unroll
  for (int i = 0; i < 4; i++)
    tile[ty + i * 8][tx] = src[(size_t)(rb + ty + i * 8) * N + cb + tx];
  __syncthreads();
#pragma unroll
  for (int i = 0; i < 4; i++)
    dst[(size_t)(cb + ty + i * 8) * M + rb + tx] = f2b(tile[tx][ty + i * 8]);
}

// ---------------- routing: single-block deterministic counting sort --------
__launch_bounds__(1024)
__global__ void k_route(const int* __restrict__ te, const float* __restrict__ tw,
                        int* __restrict__ ctrl, int* __restrict__ perm,
                        float* __restrict__ pw, int* __restrict__ tileE,
                        int* __restrict__ tileRow, int* __restrict__ inv) {
  __shared__ int wsum[17][EE];
  __shared__ int ebase[EE];
  int tid = threadIdx.x;
  int lane = tid & 63, wid = tid >> 6;
  int myte[16]; float mytw[16];
  int c[EE];
#pragma unroll
  for (int e = 0; e < EE; e++) c[e] = 0;
  int s0 = tid * 16;
#pragma unroll
  for (int j = 0; j < 16; j++) {
    myte[j] = te[s0 + j];
    mytw[j] = tw[s0 + j];
#pragma unroll
    for (int e = 0; e < EE; e++) if (myte[j] == e) c[e]++;
  }
  int incl[EE];
#pragma unroll
  for (int e = 0; e < EE; e++) incl[e] = c[e];
  for (int off = 1; off < 64; off <<= 1) {
#pragma unroll
    for (int e = 0; e < EE; e++) {
      int v = __shfl_up(incl[e], off);
      if (lane >= off) incl[e] += v;
    }
  }
  if (lane == 63)
#pragma unroll
    for (int e = 0; e < EE; e++) wsum[wid][e] = incl[e];
  __syncthreads();
  if (tid < EE) {
    int s = 0;
    for (int w = 0; w < 16; w++) { int v = wsum[w][tid]; wsum[w][tid] = s; s += v; }
    wsum[16][tid] = s;
  }
  __syncthreads();
  if (tid == 0) {
    int s = 0, nt = 0;
    for (int e = 0; e < EE; e++) {
      int cnt = wsum[16][e];
      ebase[e] = s; ctrl[8 + e] = s; ctrl[e] = cnt;
      for (int i = 0; i < cnt; i += 128) { tileE[nt] = e; tileRow[nt] = s + i; nt++; }
      s += cnt;
    }
    ctrl[16] = s; ctrl[17] = nt;
  }
  __syncthreads();
#pragma unroll
  for (int e = 0; e < EE; e++) {
    int p = ebase[e] + wsum[wid][e] + incl[e] - c[e];
#pragma unroll
    for (int j = 0; j < 16; j++) {
      if (myte[j] == e) {
        perm[p] = (s0 + j) >> 1;
        pw[p] = mytw[j];
        inv[s0 + j] = p;
        p++;
      }
    }
  }
}

// ---------------- GEMM1: h[pos][f] = pw * silu(x@W) * (x@V) -----------------
// BM=128 rows x 128 F-cols (W and V -> 256 LDS B-rows), BK=32, 4 waves 2Mx2N.
// 3-buffer ring, 2-step lookahead, counted vmcnt, raw s_barrier. (round-9)
__launch_bounds__(256, 2)
__global__ void k_ffn1(const unsigned short* __restrict__ xb,
                       const unsigned short* __restrict__ Wt,
                       const unsigned short* __restrict__ Vt,
                       const int* __restrict__ perm, const float* __restrict__ pw,
                       const int* __restrict__ ctrl, const int* __restrict__ tileE,
                       const int* __restrict__ tileRow,
                       unsigned short* __restrict__ h) {
  int ti = blockIdx.y;
  if (ti >= ctrl[17]) return;
  int e = tileE[ti];
  int row0 = tileRow[ti];
  int last = ctrl[8 + e] + ctrl[e] - 1;
  int f0 = blockIdx.x * 128;

  __shared__ __align__(16) short As[3][128 * 32];   // 8 KB per buf
  __shared__ __align__(16) short Bs[3][256 * 32];   // 16 KB per buf

  int tid = threadIdx.x;
  int lane = tid & 63, wid = tid >> 6;
  int wr = wid >> 1, wc = wid & 1;

  int sl = (((tid & 3) ^ ((tid >> 3) & 3))) * 8;

  int ar1 = row0 + (tid >> 2); if (ar1 > last) ar1 = last;
  int ar2 = row0 + (tid >> 2) + 64; if (ar2 > last) ar2 = last;
  const unsigned short* agp1 = xb + (size_t)perm[ar1] * DD + sl;
  const unsigned short* agp2 = xb + (size_t)perm[ar2] * DD + sl;
  const unsigned short* wgp1 = Wt + ((size_t)e * FF + f0 + (tid >> 2)) * DD + sl;
  const unsigned short* wgp2 = wgp1 + (size_t)64 * DD;
  const unsigned short* vgp1 = Vt + ((size_t)e * FF + f0 + (tid >> 2)) * DD + sl;
  const unsigned short* vgp2 = vgp1 + (size_t)64 * DD;

#define STAGE1(buf, k0) do { \
    gload16(agp1 + (k0), &As[buf][tid * 8]); \
    gload16(agp2 + (k0), &As[buf][(tid + 256) * 8]); \
    gload16(wgp1 + (k0), &Bs[buf][tid * 8]); \
    gload16(wgp2 + (k0), &Bs[buf][(tid + 256) * 8]); \
    gload16(vgp1 + (k0), &Bs[buf][(tid + 512) * 8]); \
    gload16(vgp2 + (k0), &Bs[buf][(tid + 768) * 8]); \
  } while (0)

  f32x4 zz = {0.f, 0.f, 0.f, 0.f};
  f32x4 accw[4][4], accv[4][4];
#pragma unroll
  for (int m = 0; m < 4; m++)
#pragma unroll
    for (int n = 0; n < 4; n++) { accw[m][n] = zz; accv[m][n] = zz; }

  int lrow = lane & 15;
  int jx = (((lane >> 4) ^ ((lane >> 1) & 3))) * 8;

#define COMP1(buf) do { \
    bf16x8 a[4], bw[4], bv[4]; \
    _Pragma("unroll") \
    for (int m = 0; m < 4; m++) a[m] = *(bf16x8*)&As[buf][(wr * 64 + m * 16 + lrow) * 32 + jx]; \
    _Pragma("unroll") \
    for (int n = 0; n < 4; n++) { \
      bw[n] = *(bf16x8*)&Bs[buf][(wc * 64 + n * 16 + lrow) * 32 + jx]; \
      bv[n] = *(bf16x8*)&Bs[buf][(128 + wc * 64 + n * 16 + lrow) * 32 + jx]; \
    } \
    _Pragma("unroll") \
    for (int m = 0; m < 4; m++) \
      _Pragma("unroll") \
      for (int n = 0; n < 4; n++) { \
        accw[m][n] = __builtin_amdgcn_mfma_f32_16x16x32_bf16(a[m], bw[n], accw[m][n], 0, 0, 0); \
        accv[m][n] = __builtin_amdgcn_mfma_f32_16x16x32_bf16(a[m], bv[n], accv[m][n], 0, 0, 0); \
      } \
  } while (0)

  // prologue: fill the 3-deep ring (18 loads in flight)
  STAGE1(0, 0); STAGE1(1, 32); STAGE1(2, 64);
#pragma unroll 1
  for (int kt = 0; kt < 4; kt++) {   // ks = 0..11, stages k3..k14
    VMCNT12; BARX; COMP1(0); BARX; STAGE1(0, (kt * 3 + 3) * 32);
    VMCNT12; BARX; COMP1(1); BARX; STAGE1(1, (kt * 3 + 4) * 32);
    VMCNT12; BARX; COMP1(2); BARX; STAGE1(2, (kt * 3 + 5) * 32);
  }
  VMCNT12; BARX; COMP1(0); BARX; STAGE1(0, 15 * 32);  // ks=12, stages k15
  VMCNT12; BARX; COMP1(1);                            // ks=13
  VMCNT6;  BARX; COMP1(2);                            // ks=14
  VMCNT0;  BARX; COMP1(0);                            // ks=15
#undef STAGE1
#undef COMP1

#pragma unroll
  for (int m = 0; m < 4; m++) {
    int rbase = row0 + wr * 64 + m * 16 + (lane >> 4) * 4;
#pragma unroll
    for (int reg = 0; reg < 4; reg++) {
      int r = rbase + reg;
      if (r > last) continue;
      float pwv = pw[r];
      size_t hrow = (size_t)r * FF;
#pragma unroll
      for (int n = 0; n < 4; n++) {
        float a = accw[m][n][reg];
        float b = accv[m][n][reg];
        float hv = a / (1.f + __expf(-a)) * b * pwv;
        h[hrow + f0 + wc * 64 + n * 16 + lrow] = f2b(hv);
      }
    }
  }
}

// ---------------- GEMM2 (split-K=2): yp2[kh][pos][d] = h[pos][kh-half] @ W2t -
// 128x128 tile, 32 K-steps per half, 4 waves 2x2, acc[4][4], 2-stage dbuf.
// 1088 blocks -> 4.25 blocks/CU (was 544 -> 2.125, 1.41x imbalance stretch).
__launch_bounds__(256)
__global__ void k_ffn2(const unsigned short* __restrict__ h,
                       const unsigned short* __restrict__ W2t,
                       const int* __restrict__ ctrl,
                       const int* __restrict__ tileE, const int* __restrict__ tileRow,
                       unsigned short* __restrict__ yp) {
  int ti = blockIdx.y;
  if (ti >= ctrl[17]) return;
  int e = tileE[ti];
  int row0 = tileRow[ti];
  int last = ctrl[8 + e] + ctrl[e] - 1;
  int d0 = blockIdx.x * 128;
  int kh = blockIdx.z;
  int kb = kh * 1024;          // element offset of this K-half

  __shared__ __align__(16) short As[2][128 * 32];
  __shared__ __align__(16) short Bs[2][128 * 32];

  int tid = threadIdx.x;
  int lane = tid & 63, wid = tid >> 6;
  int wm = (wid >> 1) * 64, wn = (wid & 1) * 64;

  int sl = (((tid & 3) ^ ((tid >> 3) & 3))) * 8;

  int ar1 = row0 + (tid >> 2); if (ar1 > last) ar1 = last;
  int ar2 = row0 + (tid >> 2) + 64; if (ar2 > last) ar2 = last;
  const unsigned short* agp1 = h + (size_t)ar1 * FF + kb + sl;
  const unsigned short* agp2 = h + (size_t)ar2 * FF + kb + sl;
  const unsigned short* bgp1 = W2t + ((size_t)e * DD + d0 + (tid >> 2)) * FF + kb + sl;
  const unsigned short* bgp2 = bgp1 + (size_t)64 * FF;

#define STAGE2(buf, k0) do { \
    gload16(agp1 + (k0), &As[buf][tid * 8]); \
    gload16(agp2 + (k0), &As[buf][(tid + 256) * 8]); \
    gload16(bgp1 + (k0), &Bs[buf][tid * 8]); \
    gload16(bgp2 + (k0), &Bs[buf][(tid + 256) * 8]); \
  } while (0)

  f32x4 zz = {0.f, 0.f, 0.f, 0.f};
  f32x4 acc[4][4];
#pragma unroll
  for (int m = 0; m < 4; m++)
#pragma unroll
    for (int n = 0; n < 4; n++) acc[m][n] = zz;

  int lrow = lane & 15;
  int jx = (((lane >> 4) ^ ((lane >> 1) & 3))) * 8;

#define COMP2(buf) do { \
    bf16x8 a[4], b[4]; \
    _Pragma("unroll") \
    for (int m = 0; m < 4; m++) a[m] = *(bf16x8*)&As[buf][(wm + m * 16 + lrow) * 32 + jx]; \
    _Pragma("unroll") \
    for (int n = 0; n < 4; n++) b[n] = *(bf16x8*)&Bs[buf][(wn + n * 16 + lrow) * 32 + jx]; \
    _Pragma("unroll") \
    for (int m = 0; m < 4; m++) \
      _Pragma("unroll") \
      for (int n = 0; n < 4; n++) \
        acc[m][n] = __builtin_amdgcn_mfma_f32_16x16x32_bf16(a[m], b[n], acc[m][n], 0, 0, 0); \
  } while (0)

  STAGE2(0, 0);
  __syncthreads();
#pragma unroll 1
  for (int ks = 0; ks < 32; ks += 2) {
    STAGE2(1, (ks + 1) * 32);        // ks+1 <= 31 always
    COMP2(0);
    __syncthreads();
    if (ks + 2 < 32) STAGE2(0, (ks + 2) * 32);
    COMP2(1);
    __syncthreads();
  }
#undef STAGE2
#undef COMP2

#pragma unroll
  for (int m = 0; m < 4; m++) {
    int rbase = row0 + wm + m * 16 + (lane >> 4) * 4;
#pragma unroll
    for (int reg = 0; reg < 4; reg++) {
      int r = rbase + reg;
      if (r > last) continue;
      unsigned short* ypr = yp + ((size_t)kh * (TT * 2) + r) * DD + d0;
#pragma unroll
      for (int n = 0; n < 4; n++)
        ypr[wn + n * 16 + lrow] = f2b(acc[m][n][reg]);
    }
  }
}

// -------- gather: y[t] = sum_kh ( yp2[kh][inv[2t]] + yp2[kh][inv[2t+1]] ) ----
__launch_bounds__(256)
__global__ void k_gather(const unsigned short* __restrict__ yp,
                         const int* __restrict__ inv, float* __restrict__ y) {
  int i = blockIdx.x * 256 + threadIdx.x;   // over TT*64 groups of 8 cols
  int t = i >> 6, seg = (i & 63) * 8;
  int pa = inv[2 * t], pb = inv[2 * t + 1];
  const unsigned short* y1 = yp + (size_t)(TT * 2) * DD;
  bf16x8 a0 = *(const bf16x8*)(yp + (size_t)pa * DD + seg);
  bf16x8 b0 = *(const bf16x8*)(yp + (size_t)pb * DD + seg);
  bf16x8 a1 = *(const bf16x8*)(y1 + (size_t)pa * DD + seg);
  bf16x8 b1 = *(const bf16x8*)(y1 + (size_t)pb * DD + seg);
  float* yr = y + (size_t)t * DD + seg;
  float4 o0, o1;
  o0.x = (b2f((unsigned short)a0[0]) + b2f((unsigned short)a1[0])) + (b2f((unsigned short)b0[0]) + b2f((unsigned short)b1[0]));
  o0.y = (b2f((unsigned short)a0[1]) + b2f((unsigned short)a1[1])) + (b2f((unsigned short)b0[1]) + b2f((unsigned short)b1[1]));
  o0.z = (b2f((unsigned short)a0[2]) + b2f((unsigned short)a1[2])) + (b2f((unsigned short)b0[2]) + b2f((unsigned short)b1[2]));
  o0.w = (b2f((unsigned short)a0[3]) + b2f((unsigned short)a1[3])) + (b2f((unsigned short)b0[3]) + b2f((unsigned short)b1[3]));
  o1.x = (b2f((unsigned short)a0[4]) + b2f((unsigned short)a1[4])) + (b2f((unsigned short)b0[4]) + b2f((unsigned short)b1[4]));
  o1.y = (b2f((unsigned short)a0[5]) + b2f((unsigned short)a1[5])) + (b2f((unsigned short)b0[5]) + b2f((unsigned short)b1[5]));
  o1.z = (b2f((unsigned short)a0[6]) + b2f((unsigned short)a1[6])) + (b2f((unsigned short)b0[6]) + b2f((unsigned short)b1[6]));
  o1.w = (b2f((unsigned short)a0[7]) + b2f((unsigned short)a1[7])) + (b2f((unsigned short)b0[7]) + b2f((unsigned short)b1[7]));
  *(float4*)yr = o0;
  *(float4*)(yr + 4) = o1;
}

extern "C" void kernel_launch(void* const* d_in, const int* in_sizes, int n_in,
                              void* d_out, int out_size, void* d_ws, size_t ws_size,
                              hipStream_t stream) {
  const float* x  = (const float*)d_in[0];
  const float* Wg = (const float*)d_in[1];
  const float* W  = (const float*)d_in[2];
  const float* V  = (const float*)d_in[3];
  const float* W2 = (const float*)d_in[4];
  float* y = (float*)d_out;

  char* ws = (char*)d_ws;
  size_t off = 0;
  auto alloc = [&](size_t n) -> char* {
    char* p = ws + off;
    off += (n + 255) & ~(size_t)255;
    return p;
  };
  unsigned short* xb  = (unsigned short*)alloc((size_t)TT * DD * 2);
  unsigned short* Wt  = (unsigned short*)alloc((size_t)EE * DD * FF * 2);
  unsigned short* Vt  = (unsigned short*)alloc((size_t)EE * DD * FF * 2);
  unsigned short* W2t = (unsigned short*)alloc((size_t)EE * DD * FF * 2);
  unsigned short* h   = (unsigned short*)alloc((size_t)TT * 2 * FF * 2);
  int*   perm = (int*)alloc(TT * 2 * 4);
  float* pw   = (float*)alloc(TT * 2 * 4);
  int*   te   = (int*)alloc(TT * 2 * 4);
  float* tw   = (float*)alloc(TT * 2 * 4);
  int*   inv  = (int*)alloc(TT * 2 * 4);
  int*   ctrl = (int*)alloc(256);
  int*   tileE   = (int*)alloc(MAXT * 4);
  int*   tileRow = (int*)alloc(MAXT * 4);
  if (off > ws_size) return;

  // yp2 = [2][TT*2][DD] bf16 = 33.55 MB; aliases Wt+Vt exactly (each 16.78 MB,
  // 256B-aligned contiguous, both dead after ffn1).
  unsigned short* yp = (unsigned short*)Wt;

  k_prep<<<TT / 4, 256, 0, stream>>>(x, Wg, xb, te, tw);
  k_tcvt_all<<<dim3(1024, 24), dim3(32, 8), 0, stream>>>(W, V, W2, Wt, Vt, W2t);
  k_route<<<1, 1024, 0, stream>>>(te, tw, ctrl, perm, pw, tileE, tileRow, inv);
  k_ffn1<<<dim3(FF / 128, MAXT), 256, 0, stream>>>(xb, Wt, Vt, perm, pw, ctrl, tileE, tileRow, h);
  k_ffn2<<<dim3(DD / 128, MAXT, 2), 256, 0, stream>>>(h, W2t, ctrl, tileE, tileRow, yp);
  k_gather<<<TT * 64 / 256, 256, 0, stream>>>(yp, inv, y);
}